// Round 3
// baseline (12.254 us; speedup 1.0000x reference)
//
#include <hip/hip_runtime.h>
#include <hip/hip_bf16.h>
#include <math.h>

// SkipGram with sparse-mask structure:
// masked[i, j] = emb[i, j] iff (j - i) in OFFSETS = {0,12,19,24,28,31,34,36}
// score[b] = sum over pairs (i,j) with OFF[i]-OFF[j] == context[b]-focus[b]
//            of emb[f, f+OFF[i]] * emb[c, c+OFF[j]]
// out[b] = log_sigmoid(score[b])
//
// ~99.5% of random (f,c) pairs have d = c-f outside the offset-difference
// set -> score == 0 -> out = -ln2 with zero row loads. 4 elements/thread,
// int4 index loads + float4 stores to minimize the latency chain.

#define EMBED_SIZE 8228

__device__ __forceinline__ float log_sigmoid_f(float x) {
    return fminf(x, 0.0f) - log1pf(expf(-fabsf(x)));
}

__device__ __forceinline__ float score_one(int f, int c, const float* __restrict__ emb) {
    constexpr int OFF[8] = {0, 12, 19, 24, 28, 31, 34, 36};
    constexpr unsigned long long DIFF_MASK =
        (1ULL<<0)|(1ULL<<2)|(1ULL<<3)|(1ULL<<4)|(1ULL<<5)|(1ULL<<6)|(1ULL<<7)|
        (1ULL<<8)|(1ULL<<9)|(1ULL<<10)|(1ULL<<12)|(1ULL<<15)|(1ULL<<16)|(1ULL<<17)|
        (1ULL<<19)|(1ULL<<22)|(1ULL<<24)|(1ULL<<28)|(1ULL<<31)|(1ULL<<34)|(1ULL<<36);

    int d = c - f;
    int ad = abs(d);
    float result = -0.6931471805599453f;  // log_sigmoid(0) = -ln 2

    if (ad <= 36 && ((DIFF_MASK >> ad) & 1ULL)) {
        const float* rf = emb + (long long)f * EMBED_SIZE + f;
        const float* rc = emb + (long long)c * EMBED_SIZE + c;
        float ef[8], ec[8];
#pragma unroll
        for (int i = 0; i < 8; ++i) {
            ef[i] = rf[OFF[i]];
            ec[i] = rc[OFF[i]];
        }
        float acc = 0.0f;
#pragma unroll
        for (int i = 0; i < 8; ++i) {
#pragma unroll
            for (int j = 0; j < 8; ++j) {
                acc += (d == (OFF[i] - OFF[j])) ? ef[i] * ec[j] : 0.0f;
            }
        }
        result = log_sigmoid_f(acc);
    }
    return result;
}

__global__ __launch_bounds__(256) void skipgram_kernel(
    const int4* __restrict__ focus4,
    const int4* __restrict__ ctx4,
    const float* __restrict__ emb,
    float4* __restrict__ out4,
    int B4)
{
    int t = blockIdx.x * blockDim.x + threadIdx.x;
    if (t >= B4) return;

    int4 f = focus4[t];
    int4 c = ctx4[t];

    float4 r;
    r.x = score_one(f.x, c.x, emb);
    r.y = score_one(f.y, c.y, emb);
    r.z = score_one(f.z, c.z, emb);
    r.w = score_one(f.w, c.w, emb);

    out4[t] = r;
}

extern "C" void kernel_launch(void* const* d_in, const int* in_sizes, int n_in,
                              void* d_out, int out_size, void* d_ws, size_t ws_size,
                              hipStream_t stream) {
    const int*   focus   = (const int*)d_in[0];
    const int*   context = (const int*)d_in[1];
    const float* emb     = (const float*)d_in[2];
    float*       out     = (float*)d_out;

    int B  = in_sizes[0];   // 8192, divisible by 4
    int B4 = B / 4;         // 2048
    int block = 256;
    int grid = (B4 + block - 1) / block;  // 8
    skipgram_kernel<<<grid, block, 0, stream>>>(
        (const int4*)focus, (const int4*)context, emb, (float4*)out, B4);
}

// Round 4
// 9.899 us; speedup vs baseline: 1.2379x; 1.2379x over previous
//
#include <hip/hip_runtime.h>
#include <hip/hip_bf16.h>
#include <math.h>

// SkipGram with sparse-mask structure:
// masked[i, j] = emb[i, j] iff (j - i) in OFFSETS = {0,12,19,24,28,31,34,36}
// score[b] = sum over pairs (i,j) with OFF[i]-OFF[j] == context[b]-focus[b]
//            of emb[f, f+OFF[i]] * emb[c, c+OFF[j]]
// out[b] = log_sigmoid(score[b])
//
// ~99.5% of random (f,c) pairs have d = c-f outside the offset-difference
// set -> score == 0 -> out = -ln2 with zero row loads.
// Round-3 post-mortem: 4-elem/thread (8 blocks) regressed 9.4->12.25 us —
// longer dependent chains per thread lose at latency scale. This is the
// round-2 structure: 1 elem/thread, 32 blocks x 256.

#define EMBED_SIZE 8228

__device__ __forceinline__ float log_sigmoid_f(float x) {
    // stable: min(x,0) - log1p(exp(-|x|))
    return fminf(x, 0.0f) - log1pf(expf(-fabsf(x)));
}

__global__ __launch_bounds__(256) void skipgram_kernel(
    const int* __restrict__ focus,
    const int* __restrict__ context,
    const float* __restrict__ emb,
    float* __restrict__ out,
    int B)
{
    constexpr int OFF[8] = {0, 12, 19, 24, 28, 31, 34, 36};
    // |OFF[i]-OFF[j]| in {0,2..10,12,15,16,17,19,22,24,28,31,34,36}; split
    // into two 32-bit masks to avoid a 64-bit shift.
    constexpr unsigned MASK_LO =
        (1u<<0)|(1u<<2)|(1u<<3)|(1u<<4)|(1u<<5)|(1u<<6)|(1u<<7)|
        (1u<<8)|(1u<<9)|(1u<<10)|(1u<<12)|(1u<<15)|(1u<<16)|(1u<<17)|
        (1u<<19)|(1u<<22)|(1u<<24)|(1u<<28)|(1u<<31);
    constexpr unsigned MASK_HI = (1u<<(34-32))|(1u<<(36-32));  // 34, 36

    int b = blockIdx.x * blockDim.x + threadIdx.x;
    if (b >= B) return;

    int f = focus[b];
    int c = context[b];
    int d = c - f;
    int ad = abs(d);

    float result = -0.6931471805599453f;  // log_sigmoid(0) = -ln 2

    bool hit = (ad < 32) ? ((MASK_LO >> ad) & 1u)
                         : (ad <= 36 && ((MASK_HI >> (ad - 32)) & 1u));
    if (hit) {
        // Rare path (~0.5% of threads): masked-row dot product.
        const float* rf = emb + (long long)f * EMBED_SIZE + f;
        const float* rc = emb + (long long)c * EMBED_SIZE + c;

        float ef[8], ec[8];
#pragma unroll
        for (int i = 0; i < 8; ++i) {
            ef[i] = rf[OFF[i]];
            ec[i] = rc[OFF[i]];
        }

        float acc = 0.0f;
#pragma unroll
        for (int i = 0; i < 8; ++i) {
#pragma unroll
            for (int j = 0; j < 8; ++j) {
                acc += (d == (OFF[i] - OFF[j])) ? ef[i] * ec[j] : 0.0f;
            }
        }
        result = log_sigmoid_f(acc);
    }

    out[b] = result;
}

extern "C" void kernel_launch(void* const* d_in, const int* in_sizes, int n_in,
                              void* d_out, int out_size, void* d_ws, size_t ws_size,
                              hipStream_t stream) {
    const int*   focus   = (const int*)d_in[0];
    const int*   context = (const int*)d_in[1];
    const float* emb     = (const float*)d_in[2];
    float*       out     = (float*)d_out;

    int B = in_sizes[0];  // 8192
    int block = 256;
    int grid = (B + block - 1) / block;  // 32
    skipgram_kernel<<<grid, block, 0, stream>>>(focus, context, emb, out, B);
}